// Round 7
// baseline (277.535 us; speedup 1.0000x reference)
//
#include <hip/hip_runtime.h>
#include <hip/hip_bf16.h>

#define BB 32
#define IDF 64
#define CDF 256
#define SSZ 1024
#define NH 8
#define LL 256
#define KHC 2048   // NH*CDF

typedef __attribute__((ext_vector_type(8))) short short8v;   // 8 bf16 (4 VGPR)
typedef __attribute__((ext_vector_type(4))) float f32x4;     // MFMA acc

__device__ inline void split_bf16(float x, __hip_bfloat16& h, __hip_bfloat16& l) {
  h = __float2bfloat16(x);
  l = __float2bfloat16(x - __bfloat162float(h));
}

// ---------------------------------------------------------------------------
// Split wc (fp32) -> wch, wcl (bf16 hi/lo), same [b][i][o] layout.
// ---------------------------------------------------------------------------
__global__ __launch_bounds__(256) void k_split_wc(const float* __restrict__ wc,
                                                  __hip_bfloat16* __restrict__ wch,
                                                  __hip_bfloat16* __restrict__ wcl) {
  int idx = (blockIdx.x * 256 + threadIdx.x) * 4;
  float4 v = *reinterpret_cast<const float4*>(&wc[idx]);
  __align__(16) __hip_bfloat16 hb[4], lb[4];
  split_bf16(v.x, hb[0], lb[0]); split_bf16(v.y, hb[1], lb[1]);
  split_bf16(v.z, hb[2], lb[2]); split_bf16(v.w, hb[3], lb[3]);
  *reinterpret_cast<int2*>(&wch[idx]) = *reinterpret_cast<int2*>(hb);
  *reinterpret_cast<int2*>(&wcl[idx]) = *reinterpret_cast<int2*>(lb);
}

// ---------------------------------------------------------------------------
// Split W (fp32, [h][o][c]) -> Wh, Wl (bf16, same layout). For K4.
// ---------------------------------------------------------------------------
__global__ __launch_bounds__(256) void k_split_W(const float* __restrict__ W,
                                                 __hip_bfloat16* __restrict__ Wh,
                                                 __hip_bfloat16* __restrict__ Wl) {
  int idx = (blockIdx.x * 256 + threadIdx.x) * 4;
  float4 v = *reinterpret_cast<const float4*>(&W[idx]);
  __align__(16) __hip_bfloat16 hb[4], lb[4];
  split_bf16(v.x, hb[0], lb[0]); split_bf16(v.y, hb[1], lb[1]);
  split_bf16(v.z, hb[2], lb[2]); split_bf16(v.w, hb[3], lb[3]);
  *reinterpret_cast<int2*>(&Wh[idx]) = *reinterpret_cast<int2*>(hb);
  *reinterpret_cast<int2*>(&Wl[idx]) = *reinterpret_cast<int2*>(lb);
}

// ---------------------------------------------------------------------------
// Split+transpose W[h][o][c] (fp32) -> Wt hi/lo [h][c][o] (bf16). For K1.
// ---------------------------------------------------------------------------
__global__ __launch_bounds__(256) void k_split_Wt(const float* __restrict__ W,
                                                  __hip_bfloat16* __restrict__ wth,
                                                  __hip_bfloat16* __restrict__ wtl) {
  __shared__ float Tt[64][65];   // [c][o]
  int blk = blockIdx.x;
  int h = blk >> 6, ot = (blk >> 2) & 15, ct = blk & 3;
  int og = ot * 64, cg = ct * 64;
  int t = threadIdx.x;
  int o_l = t >> 4, c4 = (t & 15) * 4;
#pragma unroll
  for (int p = 0; p < 4; ++p) {
    int o = o_l + 16 * p;
    float4 v = *reinterpret_cast<const float4*>(
        &W[((size_t)h * SSZ + og + o) * CDF + cg + c4]);
    Tt[c4 + 0][o] = v.x; Tt[c4 + 1][o] = v.y;
    Tt[c4 + 2][o] = v.z; Tt[c4 + 3][o] = v.w;
  }
  __syncthreads();
  int c_l = t >> 2;
#pragma unroll
  for (int p = 0; p < 4; ++p) {
    int oq = (t & 3) + 4 * p;
    int o0 = oq * 4;
    __hip_bfloat16 hv[4], lv[4];
#pragma unroll
    for (int j = 0; j < 4; ++j)
      split_bf16(Tt[c_l][o0 + j], hv[j], lv[j]);
    size_t base = ((size_t)h * CDF + cg + c_l) * SSZ + og + o0;
#pragma unroll
    for (int j = 0; j < 4; ++j) { wth[base + j] = hv[j]; wtl[base + j] = lv[j]; }
  }
}

// ---------------------------------------------------------------------------
// K1 (MFMA, LDS-free direct fragments): M[bh][i][c] = sum_o wc[b][i][o]*W[h][o][c]
// grid 512: (bh, nh-half of 128c). 4 waves x (64i x 32c). No LDS, no barriers.
// Fragment = 16B global load: lane l holds row (l&15), k = (l>>4)*8 + j.
// 1-deep register prefetch via two named sets (static indexing).
// ---------------------------------------------------------------------------
#define K1_STEP(KS, CAH, CAL, CBH, CBL, NAH, NAL, NBH, NBL)                    \
  {                                                                            \
    if ((KS) < 31) {                                                           \
      int nk0 = ((KS) + 1) * 32;                                               \
      _Pragma("unroll")                                                        \
      for (int r = 0; r < 4; ++r) {                                            \
        NAH[r] = *reinterpret_cast<const short8v*>(&gA_h[offA[r] + nk0]);      \
        NAL[r] = *reinterpret_cast<const short8v*>(&gA_l[offA[r] + nk0]);      \
      }                                                                        \
      _Pragma("unroll")                                                        \
      for (int c = 0; c < 2; ++c) {                                            \
        NBH[c] = *reinterpret_cast<const short8v*>(&gB_h[offB[c] + nk0]);      \
        NBL[c] = *reinterpret_cast<const short8v*>(&gB_l[offB[c] + nk0]);      \
      }                                                                        \
    }                                                                          \
    _Pragma("unroll")                                                          \
    for (int r = 0; r < 4; ++r)                                                \
      _Pragma("unroll")                                                        \
      for (int c = 0; c < 2; ++c) {                                            \
        acc[r][c] = __builtin_amdgcn_mfma_f32_16x16x32_bf16(CAH[r], CBH[c], acc[r][c], 0, 0, 0); \
        acc[r][c] = __builtin_amdgcn_mfma_f32_16x16x32_bf16(CAH[r], CBL[c], acc[r][c], 0, 0, 0); \
        acc[r][c] = __builtin_amdgcn_mfma_f32_16x16x32_bf16(CAL[r], CBH[c], acc[r][c], 0, 0, 0); \
      }                                                                        \
  }

__global__ __launch_bounds__(256) void k1_mfma(const __hip_bfloat16* __restrict__ wch,
                                               const __hip_bfloat16* __restrict__ wcl,
                                               const __hip_bfloat16* __restrict__ wth,
                                               const __hip_bfloat16* __restrict__ wtl,
                                               float* __restrict__ Mout) {
  int blk = blockIdx.x;
  int bh = blk >> 1, nh = blk & 1;
  int b = bh >> 3, h = bh & 7;
  int t = threadIdx.x;
  int lane = t & 63, wave = t >> 6;
  int ln15 = lane & 15, kh = lane >> 4;

  const short* gA_h = (const short*)wch + (size_t)b * IDF * SSZ;
  const short* gA_l = (const short*)wcl + (size_t)b * IDF * SSZ;
  const short* gB_h = (const short*)wth + (size_t)(h * CDF + nh * 128) * SSZ;
  const short* gB_l = (const short*)wtl + (size_t)(h * CDF + nh * 128) * SSZ;

  int offA[4], offB[2];
#pragma unroll
  for (int r = 0; r < 4; ++r) offA[r] = (r * 16 + ln15) * SSZ + kh * 8;
#pragma unroll
  for (int c = 0; c < 2; ++c) offB[c] = (wave * 32 + c * 16 + ln15) * SSZ + kh * 8;

  f32x4 acc[4][2] = {};
  short8v a0h[4], a0l[4], b0h[2], b0l[2];
  short8v a1h[4], a1l[4], b1h[2], b1l[2];

  // prologue: load k-step 0 into set0
#pragma unroll
  for (int r = 0; r < 4; ++r) {
    a0h[r] = *reinterpret_cast<const short8v*>(&gA_h[offA[r]]);
    a0l[r] = *reinterpret_cast<const short8v*>(&gA_l[offA[r]]);
  }
#pragma unroll
  for (int c = 0; c < 2; ++c) {
    b0h[c] = *reinterpret_cast<const short8v*>(&gB_h[offB[c]]);
    b0l[c] = *reinterpret_cast<const short8v*>(&gB_l[offB[c]]);
  }

#pragma unroll 1
  for (int ks = 0; ks < 32; ks += 2) {
    K1_STEP(ks,     a0h, a0l, b0h, b0l, a1h, a1l, b1h, b1l);
    K1_STEP(ks + 1, a1h, a1l, b1h, b1l, a0h, a0l, b0h, b0l);
  }

  float* out = Mout + (size_t)bh * IDF * CDF + nh * 128;
  int rowq = (lane >> 4) * 4;
#pragma unroll
  for (int r = 0; r < 4; ++r)
#pragma unroll
    for (int c = 0; c < 2; ++c)
#pragma unroll
      for (int reg = 0; reg < 4; ++reg)
        out[(r * 16 + rowq + reg) * CDF + wave * 32 + c * 16 + ln15] = acc[r][c][reg];
}

// ---------------------------------------------------------------------------
// K2: logits[bh][i][l] = sum_c M[bh][i][c] * ctx[b][c][l]; softmax over l.
// grid 512: (bh, i-half of 32). acc[4][8].
// ---------------------------------------------------------------------------
__global__ __launch_bounds__(256) void k_attn(const float* __restrict__ Mm,
                                              const float* __restrict__ ctx,
                                              float* __restrict__ attn) {
  __shared__ float As[32][32];
  __shared__ float Bs[32][LL];
  int blk = blockIdx.x;
  int bh = blk >> 1, ih = blk & 1;
  int b = bh >> 3;
  int ibase = ih * 32;
  const float* A  = Mm + ((size_t)bh * IDF + ibase) * CDF;
  const float* Bm = ctx + (size_t)b * CDF * LL;
  int tid = threadIdx.x;
  int tc = tid & 31, ti = tid >> 5;
  int c0 = tc * 8, i0 = ti * 4;
  float acc[4][8];
#pragma unroll
  for (int r = 0; r < 4; ++r)
#pragma unroll
    for (int s = 0; s < 8; ++s) acc[r][s] = 0.f;

  for (int k0 = 0; k0 < CDF; k0 += 32) {
    {                                        // A tile: 32 rows x 8 f4
      int row = tid >> 3, seg = tid & 7;
      *reinterpret_cast<float4*>(&As[row][seg * 4]) =
          *reinterpret_cast<const float4*>(&A[row * CDF + k0 + seg * 4]);
    }
#pragma unroll
    for (int p = 0; p < 8; ++p) {            // B tile: 32 rows x 64 f4
      int f = tid + p * 256;
      int kk = f >> 6, cs = f & 63;
      *reinterpret_cast<float4*>(&Bs[kk][cs * 4]) =
          *reinterpret_cast<const float4*>(&Bm[(size_t)(k0 + kk) * LL + cs * 4]);
    }
    __syncthreads();
#pragma unroll
    for (int kq = 0; kq < 8; ++kq) {
      float4 av[4];
#pragma unroll
      for (int r = 0; r < 4; ++r)
        av[r] = *reinterpret_cast<const float4*>(&As[i0 + r][kq * 4]);
#pragma unroll
      for (int kk = 0; kk < 4; ++kk) {
        float4 b0 = *reinterpret_cast<const float4*>(&Bs[kq * 4 + kk][c0]);
        float4 b1 = *reinterpret_cast<const float4*>(&Bs[kq * 4 + kk][c0 + 4]);
        float bv[8] = {b0.x, b0.y, b0.z, b0.w, b1.x, b1.y, b1.z, b1.w};
#pragma unroll
        for (int r = 0; r < 4; ++r) {
          float a = (kk == 0) ? av[r].x : (kk == 1) ? av[r].y : (kk == 2) ? av[r].z : av[r].w;
#pragma unroll
          for (int s = 0; s < 8; ++s) acc[r][s] += a * bv[s];
        }
      }
    }
    __syncthreads();
  }
  float* out = attn + ((size_t)bh * IDF + ibase) * LL;
#pragma unroll
  for (int r = 0; r < 4; ++r) {
    float mx = acc[r][0];
#pragma unroll
    for (int s = 1; s < 8; ++s) mx = fmaxf(mx, acc[r][s]);
#pragma unroll
    for (int m = 16; m >= 1; m >>= 1) mx = fmaxf(mx, __shfl_xor(mx, m, 64));
    float ex[8]; float sum = 0.f;
#pragma unroll
    for (int s = 0; s < 8; ++s) { ex[s] = __expf(acc[r][s] - mx); sum += ex[s]; }
#pragma unroll
    for (int m = 16; m >= 1; m >>= 1) sum += __shfl_xor(sum, m, 64);
    float inv = 1.f / sum;
    float4 v0 = {ex[0] * inv, ex[1] * inv, ex[2] * inv, ex[3] * inv};
    float4 v1 = {ex[4] * inv, ex[5] * inv, ex[6] * inv, ex[7] * inv};
    *reinterpret_cast<float4*>(&out[(i0 + r) * LL + c0]) = v0;
    *reinterpret_cast<float4*>(&out[(i0 + r) * LL + c0 + 4]) = v1;
  }
}

// ---------------------------------------------------------------------------
// K3: N2{h,l}[b][i][h*256+c] = split(sum_l attn[bh][i][l]*ctx[b][c][l])
// grid 512: (bh, c-half of 128). acc[4][8].
// ---------------------------------------------------------------------------
__global__ __launch_bounds__(256) void k_N2(const float* __restrict__ attn,
                                            const float* __restrict__ ctx,
                                            __hip_bfloat16* __restrict__ N2h,
                                            __hip_bfloat16* __restrict__ N2l) {
  __shared__ float As[IDF][32];    // [i][l]
  __shared__ float Bs[32][132];    // [l][c], padded
  int blk = blockIdx.x;
  int bh = blk >> 1, ch = blk & 1;
  int b = bh >> 3, h = bh & 7;
  int cgbase = ch * 128;
  const float* A  = attn + (size_t)bh * IDF * LL;
  const float* Cm = ctx + ((size_t)b * CDF + cgbase) * LL;
  int tid = threadIdx.x;
  int tc = tid & 15, ti = tid >> 4;
  int c0 = tc * 8, i0 = ti * 4;
  float acc[4][8];
#pragma unroll
  for (int r = 0; r < 4; ++r)
#pragma unroll
    for (int s = 0; s < 8; ++s) acc[r][s] = 0.f;

  for (int l0 = 0; l0 < LL; l0 += 32) {
#pragma unroll
    for (int p = 0; p < 2; ++p) {            // attn tile: 64 rows x 8 f4
      int f = tid + p * 256;
      int row = f >> 3, seg = f & 7;
      *reinterpret_cast<float4*>(&As[row][seg * 4]) =
          *reinterpret_cast<const float4*>(&A[row * LL + l0 + seg * 4]);
    }
#pragma unroll
    for (int p = 0; p < 4; ++p) {            // ctx tile: transpose-stage 128 rows
      int f = tid + p * 256;
      int c = f >> 3, seg = f & 7;
      float4 v = *reinterpret_cast<const float4*>(&Cm[(size_t)c * LL + l0 + seg * 4]);
      Bs[seg * 4 + 0][c] = v.x; Bs[seg * 4 + 1][c] = v.y;
      Bs[seg * 4 + 2][c] = v.z; Bs[seg * 4 + 3][c] = v.w;
    }
    __syncthreads();
#pragma unroll
    for (int kq = 0; kq < 8; ++kq) {
      float4 av[4];
#pragma unroll
      for (int r = 0; r < 4; ++r)
        av[r] = *reinterpret_cast<const float4*>(&As[i0 + r][kq * 4]);
#pragma unroll
      for (int kk = 0; kk < 4; ++kk) {
        float4 b0 = *reinterpret_cast<const float4*>(&Bs[kq * 4 + kk][c0]);
        float4 b1 = *reinterpret_cast<const float4*>(&Bs[kq * 4 + kk][c0 + 4]);
        float bv[8] = {b0.x, b0.y, b0.z, b0.w, b1.x, b1.y, b1.z, b1.w};
#pragma unroll
        for (int r = 0; r < 4; ++r) {
          float a = (kk == 0) ? av[r].x : (kk == 1) ? av[r].y : (kk == 2) ? av[r].z : av[r].w;
#pragma unroll
          for (int s = 0; s < 8; ++s) acc[r][s] += a * bv[s];
        }
      }
    }
    __syncthreads();
  }
  // epilogue: split to bf16 hi/lo, write [b][i][h*256 + cgbase + c]
  size_t base = (size_t)b * IDF * KHC + h * CDF + cgbase;
#pragma unroll
  for (int r = 0; r < 4; ++r) {
    __align__(16) __hip_bfloat16 hb[8], lb[8];
#pragma unroll
    for (int s = 0; s < 8; ++s) split_bf16(acc[r][s], hb[s], lb[s]);
    size_t idx = base + (size_t)(i0 + r) * KHC + c0;
    *reinterpret_cast<int4*>(&N2h[idx]) = *reinterpret_cast<int4*>(hb);
    *reinterpret_cast<int4*>(&N2l[idx]) = *reinterpret_cast<int4*>(lb);
  }
}

// ---------------------------------------------------------------------------
// K4 (MFMA, LDS-free direct fragments): ctx_out[b][i][o] = sum_{hc} N2*W
// grid 512: g(2 K-halves) x b(32) x ot(8 of 128 o). 4 waves x (64i x 32o).
// ---------------------------------------------------------------------------
#define K4_STEP(KS, CAH, CAL, CBH, CBL, NAH, NAL, NBH, NBL)                    \
  {                                                                            \
    if ((KS) < 31) {                                                           \
      int nkk0 = kbase + ((KS) + 1) * 32;                                      \
      int nh4 = nkk0 >> 8, ncb = nkk0 & 255;                                   \
      size_t wb = (size_t)nh4 * SSZ * CDF + ncb;                               \
      _Pragma("unroll")                                                        \
      for (int r = 0; r < 4; ++r) {                                            \
        NAH[r] = *reinterpret_cast<const short8v*>(&gA_h[offA[r] + nkk0]);     \
        NAL[r] = *reinterpret_cast<const short8v*>(&gA_l[offA[r] + nkk0]);     \
      }                                                                        \
      _Pragma("unroll")                                                        \
      for (int c = 0; c < 2; ++c) {                                            \
        NBH[c] = *reinterpret_cast<const short8v*>(&gB_h[wb + offB[c]]);       \
        NBL[c] = *reinterpret_cast<const short8v*>(&gB_l[wb + offB[c]]);       \
      }                                                                        \
    }                                                                          \
    _Pragma("unroll")                                                          \
    for (int r = 0; r < 4; ++r)                                                \
      _Pragma("unroll")                                                        \
      for (int c = 0; c < 2; ++c) {                                            \
        acc[r][c] = __builtin_amdgcn_mfma_f32_16x16x32_bf16(CAH[r], CBH[c], acc[r][c], 0, 0, 0); \
        acc[r][c] = __builtin_amdgcn_mfma_f32_16x16x32_bf16(CAH[r], CBL[c], acc[r][c], 0, 0, 0); \
        acc[r][c] = __builtin_amdgcn_mfma_f32_16x16x32_bf16(CAL[r], CBH[c], acc[r][c], 0, 0, 0); \
      }                                                                        \
  }

__global__ __launch_bounds__(256) void k4_mfma(const __hip_bfloat16* __restrict__ N2h,
                                               const __hip_bfloat16* __restrict__ N2l,
                                               const __hip_bfloat16* __restrict__ Wh,
                                               const __hip_bfloat16* __restrict__ Wl,
                                               float* __restrict__ out0,
                                               float* __restrict__ out1) {
  int blk = blockIdx.x;
  int g = blk >> 8;
  int r8 = blk & 255;
  int b = r8 >> 3, ot = r8 & 7;
  int obase = ot * 128;
  int t = threadIdx.x;
  int lane = t & 63, wave = t >> 6;
  int ln15 = lane & 15, kh = lane >> 4;

  const short* gA_h = (const short*)N2h + (size_t)b * IDF * KHC;
  const short* gA_l = (const short*)N2l + (size_t)b * IDF * KHC;
  const short* gB_h = (const short*)Wh;
  const short* gB_l = (const short*)Wl;

  int offA[4], offB[2];
#pragma unroll
  for (int r = 0; r < 4; ++r) offA[r] = (r * 16 + ln15) * KHC + kh * 8;
#pragma unroll
  for (int c = 0; c < 2; ++c) offB[c] = (obase + wave * 32 + c * 16 + ln15) * CDF + kh * 8;

  int kbase = g * (KHC / 2);

  f32x4 acc[4][2] = {};
  short8v a0h[4], a0l[4], b0h[2], b0l[2];
  short8v a1h[4], a1l[4], b1h[2], b1l[2];

  // prologue: load k-step 0 into set0
  {
    int kk0 = kbase;
    int h4 = kk0 >> 8, cb = kk0 & 255;
    size_t wb = (size_t)h4 * SSZ * CDF + cb;
#pragma unroll
    for (int r = 0; r < 4; ++r) {
      a0h[r] = *reinterpret_cast<const short8v*>(&gA_h[offA[r] + kk0]);
      a0l[r] = *reinterpret_cast<const short8v*>(&gA_l[offA[r] + kk0]);
    }
#pragma unroll
    for (int c = 0; c < 2; ++c) {
      b0h[c] = *reinterpret_cast<const short8v*>(&gB_h[wb + offB[c]]);
      b0l[c] = *reinterpret_cast<const short8v*>(&gB_l[wb + offB[c]]);
    }
  }

#pragma unroll 1
  for (int ks = 0; ks < 32; ks += 2) {
    K4_STEP(ks,     a0h, a0l, b0h, b0l, a1h, a1l, b1h, b1l);
    K4_STEP(ks + 1, a1h, a1l, b1h, b1l, a0h, a0l, b0h, b0l);
  }

  float* dst = (g == 0) ? out0 : out1;
  int rowq = (lane >> 4) * 4;
#pragma unroll
  for (int r = 0; r < 4; ++r)
#pragma unroll
    for (int c = 0; c < 2; ++c)
#pragma unroll
      for (int reg = 0; reg < 4; ++reg)
        dst[((size_t)b * IDF + r * 16 + rowq + reg) * SSZ +
            obase + wave * 32 + c * 16 + ln15] = acc[r][c][reg];
}

// out += P
__global__ __launch_bounds__(256) void k_add(float* __restrict__ out,
                                             const float* __restrict__ P) {
  int idx = blockIdx.x * 256 + threadIdx.x;
  float4 a = reinterpret_cast<float4*>(out)[idx];
  float4 p = reinterpret_cast<const float4*>(P)[idx];
  a.x += p.x; a.y += p.y; a.z += p.z; a.w += p.w;
  reinterpret_cast<float4*>(out)[idx] = a;
}

// ---------------------------------------------------------------------------
// K5: attn_out[b][l][i] = sum_h attn[bh][i][l]
// ---------------------------------------------------------------------------
__global__ __launch_bounds__(256) void k_attnout(const float* __restrict__ attn,
                                                 float* __restrict__ outa) {
  __shared__ float T[64][65];
  int blk = blockIdx.x; int b = blk >> 2, lt = blk & 3;
  int l0 = lt * 64;
  int tid = threadIdx.x;
  float4 acc[4];
#pragma unroll
  for (int p = 0; p < 4; ++p) acc[p] = make_float4(0.f, 0.f, 0.f, 0.f);
  for (int h = 0; h < NH; ++h) {
    const float* src = attn + (size_t)(b * NH + h) * IDF * LL;
#pragma unroll
    for (int p = 0; p < 4; ++p) {
      int f = tid + p * 256;
      int i = f >> 4, lc = (f & 15) * 4;
      float4 v = *reinterpret_cast<const float4*>(&src[i * LL + l0 + lc]);
      acc[p].x += v.x; acc[p].y += v.y; acc[p].z += v.z; acc[p].w += v.w;
    }
  }
#pragma unroll
  for (int p = 0; p < 4; ++p) {
    int f = tid + p * 256;
    int i = f >> 4, lc = (f & 15) * 4;
    T[i][lc + 0] = acc[p].x; T[i][lc + 1] = acc[p].y;
    T[i][lc + 2] = acc[p].z; T[i][lc + 3] = acc[p].w;
  }
  __syncthreads();
#pragma unroll
  for (int p = 0; p < 4; ++p) {
    int f = tid + p * 256;
    int lr = f >> 4, ic = (f & 15) * 4;
    float4 v = {T[ic + 0][lr], T[ic + 1][lr], T[ic + 2][lr], T[ic + 3][lr]};
    *reinterpret_cast<float4*>(&outa[((size_t)b * LL + l0 + lr) * IDF + ic]) = v;
  }
}

// ---------------------------------------------------------------------------
extern "C" void kernel_launch(void* const* d_in, const int* in_sizes, int n_in,
                              void* d_out, int out_size, void* d_ws, size_t ws_size,
                              hipStream_t stream) {
  const float* wc  = (const float*)d_in[0];   // [32][64][1024]
  const float* ctx = (const float*)d_in[1];   // [32][256][256]
  const float* W   = (const float*)d_in[2];   // [8][1024][256]
  float* out = (float*)d_out;

  // Region A (4.19M floats): M (fp32) -> N2h/N2l (bf16)
  float* RA = (float*)d_ws;
  // Region B (4.19M floats): wc/Wt splits -> attn -> {Pbuf, Wh/Wl}
  float* RB = RA + (size_t)4194304;

  float* Mbuf = RA;
  __hip_bfloat16* N2h = (__hip_bfloat16*)RA;                 // 4.19M bf16
  __hip_bfloat16* N2l = N2h + (size_t)BB * IDF * KHC;        // 4.19M bf16

  __hip_bfloat16* wch = (__hip_bfloat16*)RB;                 // 2.1M bf16
  __hip_bfloat16* wcl = wch + (size_t)BB * IDF * SSZ;
  __hip_bfloat16* wth = wcl + (size_t)BB * IDF * SSZ;
  __hip_bfloat16* wtl = wth + (size_t)NH * CDF * SSZ;
  float* Abuf = RB;                                          // attn, 4.19M floats
  float* Pbuf = RB;                                          // 2.1M floats
  __hip_bfloat16* Wh = (__hip_bfloat16*)(RB + (size_t)2097152);
  __hip_bfloat16* Wl = Wh + (size_t)NH * SSZ * CDF;

  k_split_wc<<<2048, 256, 0, stream>>>(wc, wch, wcl);
  k_split_Wt<<<512, 256, 0, stream>>>(W, wth, wtl);
  k1_mfma   <<<BB * NH * 2, 256, 0, stream>>>(wch, wcl, wth, wtl, Mbuf);
  k_attn    <<<BB * NH * 2, 256, 0, stream>>>(Mbuf, ctx, Abuf);
  k_N2      <<<BB * NH * 2, 256, 0, stream>>>(Abuf, ctx, N2h, N2l);
  k_attnout <<<BB * 4, 256, 0, stream>>>(Abuf, out + (size_t)BB * IDF * SSZ);
  k_split_W <<<2048, 256, 0, stream>>>(W, Wh, Wl);
  k4_mfma   <<<512, 256, 0, stream>>>(N2h, N2l, Wh, Wl, out, Pbuf);
  k_add     <<<2048, 256, 0, stream>>>(out, Pbuf);
}